// Round 1
// baseline (676.639 us; speedup 1.0000x reference)
//
#include <hip/hip_runtime.h>
#include <hip/hip_bf16.h>
#include <math.h>

// ---------------------------------------------------------------------------
// ContMixT: f_concat -> conv3x3(d2) BN ReLU -> conv3x3(d4) BN ReLU -> pool ->
// 1x1 -> fc -> per-(batch,channel) 3x3 depthwise -> two 1x1 gates -> blend.
// conv1/conv2 run as bf16 MFMA implicit GEMM (m97-style: 128x128 tile, BK=64,
// global_load_lds width=16, xor-swizzled LDS). Everything after the mean-pool
// is fp32 (error through the pool path is attenuated ~62x).
// ---------------------------------------------------------------------------

typedef __bf16 bf16x8 __attribute__((ext_vector_type(8)));
typedef float f32x4 __attribute__((ext_vector_type(4)));
typedef __attribute__((address_space(1))) void as1_void;
typedef __attribute__((address_space(3))) void as3_void;

// ---------------- small prep kernels ----------------

// BN folding: A = g/sqrt(v+eps), Bc = (conv_bias - m)*A + b  (256 threads)
__global__ __launch_bounds__(256) void prep_consts_kernel(
    const float* __restrict__ ob1, const float* __restrict__ g1, const float* __restrict__ b1,
    const float* __restrict__ m1, const float* __restrict__ v1,
    const float* __restrict__ ob2, const float* __restrict__ g2, const float* __restrict__ b2,
    const float* __restrict__ m2, const float* __restrict__ v2,
    float* __restrict__ cst)
{
  int i = threadIdx.x;
  float a1 = g1[i] / sqrtf(v1[i] + 1e-5f);
  cst[i]       = a1;
  cst[256 + i] = (ob1[i] - m1[i]) * a1 + b1[i];
  float a2 = g2[i] / sqrtf(v2[i] + 1e-5f);
  cst[512 + i] = a2;
  cst[768 + i] = (ob2[i] - m2[i]) * a2 + b2[i];
}

// NCHW fp32 x3 -> padded NHWC bf16 [b][y+2][x+2][c], c = [f_tm2 | f_tm1 | f_t]
__global__ __launch_bounds__(256) void pad_concat_kernel(
    const float* __restrict__ f2, const float* __restrict__ f1, const float* __restrict__ f0,
    __hip_bfloat16* __restrict__ out)
{
  const int b = blockIdx.x / 48, y = blockIdx.x % 48;
  __shared__ float tile[32][81];  // +1 pad breaks transpose bank conflicts
  for (int c0 = 0; c0 < 768; c0 += 32) {
    for (int idx = threadIdx.x; idx < 32 * 80; idx += 256) {
      int cl = idx / 80, x = idx - cl * 80;
      int c = c0 + cl;
      const float* src = (c < 256) ? f2 : ((c < 512) ? f1 : f0);
      int cc = c & 255;
      tile[cl][x] = src[(((size_t)b * 256 + cc) * 48 + y) * 80 + x];
    }
    __syncthreads();
    for (int idx = threadIdx.x; idx < 32 * 80; idx += 256) {
      int x = idx >> 5, cl = idx & 31;
      out[((size_t)(b * 52 + y + 2) * 84 + (x + 2)) * 768 + c0 + cl] =
          __float2bfloat16(tile[cl][x]);
    }
    __syncthreads();
  }
}

// OIHW fp32 -> [tap][oc][ic] bf16
__global__ __launch_bounds__(256) void repack_w_kernel(
    const float* __restrict__ w, __hip_bfloat16* __restrict__ out, int OC, int IC)
{
  int idx = blockIdx.x * 256 + threadIdx.x;
  if (idx >= OC * IC * 9) return;
  int ic = idx % IC;
  int t = idx / IC;
  int oc = t % OC;
  int tap = t / OC;
  out[idx] = __float2bfloat16(w[(oc * IC + ic) * 9 + tap]);
}

// gap[i][c] = mean_{y,x} Fs[i][c], Fs = [f_t ; f_t_minus_1]
__global__ __launch_bounds__(256) void gap_kernel(
    const float* __restrict__ f0, const float* __restrict__ f1, float* __restrict__ gapv)
{
  int i = blockIdx.x >> 8, c = blockIdx.x & 255;
  const float* src = (i < 8) ? (f0 + ((size_t)i * 256 + c) * 3840)
                             : (f1 + ((size_t)(i - 8) * 256 + c) * 3840);
  float s = 0.f;
  for (int k = threadIdx.x; k < 3840; k += 256) s += src[k];
  for (int off = 32; off; off >>= 1) s += __shfl_xor(s, off);
  __shared__ float red[4];
  if ((threadIdx.x & 63) == 0) red[threadIdx.x >> 6] = s;
  __syncthreads();
  if (threadIdx.x == 0)
    gapv[blockIdx.x] = (red[0] + red[1] + red[2] + red[3]) * (1.f / 3840.f);
}

// ---------------- MFMA implicit-GEMM conv ----------------
// Tile: M=128 pixels (8 rows x 16 x) x N=128 oc, BK=64, 4 waves, wave = 64x64.
// A LDS [m][64c], B LDS [oc][64c], both 128B rows with 16B-chunk xor swizzle
// (chunk col = j ^ (row&7)) so ds_read_b128 is conflict-free and the
// global_load_lds contiguous-write constraint (m104) is respected by
// permuting the *source* chunk per lane.
// MODE 0: BN+ReLU -> bf16 NHWC padded(+4) store (conv1 -> conv2 input)
// MODE 1: BN+ReLU -> pooled per-(b,oc) sums via atomics (h2 never stored)
template <int CIN, int HP, int WP, int DIL, int MODE>
__global__ __launch_bounds__(256) void conv_mfma_kernel(
    const __hip_bfloat16* __restrict__ inp, const __hip_bfloat16* __restrict__ wt,
    const float* __restrict__ bnA, const float* __restrict__ bnB,
    __hip_bfloat16* __restrict__ outp, float* __restrict__ gpool)
{
  __shared__ unsigned short As[8192] __attribute__((aligned(16)));
  __shared__ unsigned short Bs[8192] __attribute__((aligned(16)));

  int bid = blockIdx.x;
  const int ocb = bid & 1; bid >>= 1;
  const int xb = bid % 5; bid /= 5;
  const int yb = bid % 6; bid /= 6;
  const int b = bid;
  const int y0 = yb * 8, x0 = xb * 16, oc0 = ocb * 128;

  const int t = threadIdx.x;
  const int w = t >> 6, l = t & 63;
  const int col16 = l & 15, quad = l >> 4;
  const int wm = w >> 1, wn = w & 1;
  const int rsub = l >> 3;          // row within an 8-row staging chunk
  const int jj = (l & 7) ^ rsub;    // swizzled source 16B-chunk

  f32x4 acc[4][4];
  const f32x4 zf = {0.f, 0.f, 0.f, 0.f};
#pragma unroll
  for (int i = 0; i < 4; i++)
#pragma unroll
    for (int j = 0; j < 4; j++) acc[i][j] = zf;

  for (int tap = 0; tap < 9; tap++) {
    const int ty = tap / 3, tx = tap - ty * 3;
    const __hip_bfloat16* inBase =
        inp + ((size_t)(b * HP + y0 + DIL * ty) * WP + (x0 + DIL * tx)) * CIN + jj * 8;
    const __hip_bfloat16* wBase = wt + (size_t)(tap * 256 + oc0) * CIN + jj * 8;
    for (int c0 = 0; c0 < CIN; c0 += 64) {
      __syncthreads();
#pragma unroll
      for (int i = 0; i < 4; i++) {            // A: 128 pixels x 64 ch
        const int q = i * 4 + w;
        const int m = q * 8 + rsub;
        const int ry = m >> 4, rx = m & 15;
        const __hip_bfloat16* gp = inBase + (ry * WP + rx) * CIN + c0;
        __builtin_amdgcn_global_load_lds((as1_void*)gp,
            (as3_void*)((char*)As + q * 1024), 16, 0, 0);
      }
#pragma unroll
      for (int i = 0; i < 4; i++) {            // B: 128 oc x 64 ch
        const int q = i * 4 + w;
        const int n = q * 8 + rsub;
        const __hip_bfloat16* gp = wBase + n * CIN + c0;
        __builtin_amdgcn_global_load_lds((as1_void*)gp,
            (as3_void*)((char*)Bs + q * 1024), 16, 0, 0);
      }
      __syncthreads();
#pragma unroll
      for (int kiter = 0; kiter < 2; kiter++) {
        bf16x8 af[4], bg[4];
#pragma unroll
        for (int fi = 0; fi < 4; fi++) {       // A frag: m = lane&15
          const int m = wm * 64 + fi * 16 + col16;
          const int jc = (kiter * 4 + quad) ^ (m & 7);
          af[fi] = *(const bf16x8*)((const char*)As + m * 128 + jc * 16);
        }
#pragma unroll
        for (int fi = 0; fi < 4; fi++) {       // B frag: n = lane&15
          const int n = wn * 64 + fi * 16 + col16;
          const int jc = (kiter * 4 + quad) ^ (n & 7);
          bg[fi] = *(const bf16x8*)((const char*)Bs + n * 128 + jc * 16);
        }
#pragma unroll
        for (int fm_ = 0; fm_ < 4; fm_++)
#pragma unroll
          for (int fn_ = 0; fn_ < 4; fn_++)
            acc[fm_][fn_] = __builtin_amdgcn_mfma_f32_16x16x32_bf16(
                af[fm_], bg[fn_], acc[fm_][fn_], 0, 0, 0);
      }
    }
  }

  if (MODE == 0) {
    // C/D layout: col = lane&15 (= oc), row = quad*4 + r (= pixel)  [m89/m91]
#pragma unroll
    for (int fn_ = 0; fn_ < 4; fn_++) {
      const int oc = oc0 + wn * 64 + fn_ * 16 + col16;
      const float sa = bnA[oc], sb = bnB[oc];
#pragma unroll
      for (int fm_ = 0; fm_ < 4; fm_++) {
#pragma unroll
        for (int r = 0; r < 4; r++) {
          const int m = wm * 64 + fm_ * 16 + quad * 4 + r;
          const int y = y0 + (m >> 4), x = x0 + (m & 15);
          const float v = fmaxf(acc[fm_][fn_][r] * sa + sb, 0.f);
          outp[((size_t)(b * 56 + y + 4) * 88 + (x + 4)) * 256 + oc] = __float2bfloat16(v);
        }
      }
    }
  } else {
#pragma unroll
    for (int fn_ = 0; fn_ < 4; fn_++) {
      const int oc = oc0 + wn * 64 + fn_ * 16 + col16;
      const float sa = bnA[oc], sb = bnB[oc];
      float cs = 0.f;
#pragma unroll
      for (int fm_ = 0; fm_ < 4; fm_++)
#pragma unroll
        for (int r = 0; r < 4; r++)
          cs += fmaxf(acc[fm_][fn_][r] * sa + sb, 0.f);
      cs += __shfl_xor(cs, 16);   // combine the 4 quads holding this column
      cs += __shfl_xor(cs, 32);
      if (quad == 0) atomicAdd(&gpool[b * 256 + oc], cs);
    }
  }
}

// ---------------- FC chain (fp32) ----------------

// G[b][oc] = g_b[oc] + sum_c gpool[b][c]/3840 * g_w[oc][c]
__global__ __launch_bounds__(256) void fcG_kernel(
    const float* __restrict__ gpool, const float* __restrict__ gw,
    const float* __restrict__ gb, float* __restrict__ G)
{
  int b = blockIdx.x, oc = threadIdx.x;
  __shared__ float pool[256];
  pool[oc] = gpool[b * 256 + oc] * (1.f / 3840.f);
  __syncthreads();
  float s = gb[oc];
  const float* wr = gw + oc * 256;
  for (int c2 = 0; c2 < 256; c2++) s += pool[c2] * wr[c2];
  G[b * 256 + oc] = s;
}

// out1[j][i] = silu(fc_in[i] . fc1_w[j] + b[j]); fc_in = [G[i/2] | gap[i]]
__global__ __launch_bounds__(256) void fc1_kernel(
    const float* __restrict__ G, const float* __restrict__ gapv,
    const float* __restrict__ w, const float* __restrict__ bias,
    float* __restrict__ out1)
{
  __shared__ float fin[16][513];
  for (int idx = threadIdx.x; idx < 16 * 512; idx += 256) {
    int i = idx >> 9, k = idx & 511;
    fin[i][k] = (k < 256) ? G[(i >> 1) * 256 + k] : gapv[i * 256 + (k - 256)];
  }
  __syncthreads();
  int g = blockIdx.x * 256 + threadIdx.x;
  int j = g >> 4, i = g & 15;
  float s = bias[j];
  const float* wr = w + j * 512;
  for (int k = 0; k < 512; k++) s += fin[i][k] * wr[k];
  out1[j * 16 + i] = s / (1.f + expf(-s));
}

// wdw[i][j] = out1[i] . fc2_w[j] + b[j]   (j in 0..2303)
__global__ __launch_bounds__(256) void fc2_kernel(
    const float* __restrict__ out1, const float* __restrict__ w,
    const float* __restrict__ bias, float* __restrict__ wdw)
{
  __shared__ float fin[16][513];
  for (int idx = threadIdx.x; idx < 16 * 512; idx += 256) {
    int i = idx >> 9, k = idx & 511;
    fin[i][k] = out1[k * 16 + i];
  }
  __syncthreads();
  int g = blockIdx.x * 256 + threadIdx.x;
  int j = g >> 4, i = g & 15;
  float s = bias[j];
  const float* wr = w + j * 512;
  for (int k = 0; k < 512; k++) s += fin[i][k] * wr[k];
  wdw[i * 2304 + j] = s;
}

// per-(i,c) 3x3 depthwise, pad 1: fm = dwconv(Fs, wdw)
__global__ __launch_bounds__(256) void dw_kernel(
    const float* __restrict__ f0, const float* __restrict__ f1,
    const float* __restrict__ wdw, float* __restrict__ fm)
{
  int i = blockIdx.x >> 8, c = blockIdx.x & 255;
  const float* src = (i < 8) ? (f0 + ((size_t)i * 256 + c) * 3840)
                             : (f1 + ((size_t)(i - 8) * 256 + c) * 3840);
  float* dst = fm + ((size_t)i * 256 + c) * 3840;
  __shared__ float w9[9];
  if (threadIdx.x < 9) w9[threadIdx.x] = wdw[i * 2304 + c * 9 + threadIdx.x];
  __syncthreads();
  for (int p = threadIdx.x; p < 3840; p += 256) {
    int y = p / 80, x = p - y * 80;
    float s = 0.f;
#pragma unroll
    for (int ky = 0; ky < 3; ky++) {
      int yy = y + ky - 1;
      if (yy < 0 || yy >= 48) continue;
#pragma unroll
      for (int kx = 0; kx < 3; kx++) {
        int xx = x + kx - 1;
        if (xx < 0 || xx >= 80) continue;
        s += w9[ky * 3 + kx] * src[yy * 80 + xx];
      }
    }
    dst[p] = s;
  }
}

// per-pixel channel reductions -> alpha_prev, alpha planes
// (sum over f_prev folds: a_w.f_prev = ap*T1 + (1-ap)*T2, ap scalar per pixel)
__global__ __launch_bounds__(320) void alpha_kernel(
    const float* __restrict__ fm, const float* __restrict__ f2,
    const float* __restrict__ apw, const float* __restrict__ apb,
    const float* __restrict__ aw, const float* __restrict__ ab,
    float* __restrict__ planes)
{
  int b = blockIdx.x / 48, y = blockIdx.x % 48;
  int x = threadIdx.x % 80, g = threadIdx.x / 80;  // g in 0..3: 64-ch slices
  const float* ftm  = fm + ((size_t)b * 256) * 3840 + y * 80 + x;
  const float* ft1m = fm + ((size_t)(b + 8) * 256) * 3840 + y * 80 + x;
  const float* ptm2 = f2 + ((size_t)b * 256) * 3840 + y * 80 + x;
  float S = 0.f, T0 = 0.f, T1 = 0.f, T2 = 0.f;
  for (int cc = 0; cc < 64; cc++) {
    int c = g * 64 + cc;
    float v1 = ft1m[(size_t)c * 3840];
    float v2 = ptm2[(size_t)c * 3840];
    float v0 = ftm[(size_t)c * 3840];
    S  += apw[c] * v1 + apw[256 + c] * v2;
    T0 += aw[c] * v0;
    T1 += aw[256 + c] * v1;
    T2 += aw[256 + c] * v2;
  }
  __shared__ float red[4][4][80];
  red[0][g][x] = S; red[1][g][x] = T0; red[2][g][x] = T1; red[3][g][x] = T2;
  __syncthreads();
  if (g == 0) {
    S  = red[0][0][x] + red[0][1][x] + red[0][2][x] + red[0][3][x];
    T0 = red[1][0][x] + red[1][1][x] + red[1][2][x] + red[1][3][x];
    T1 = red[2][0][x] + red[2][1][x] + red[2][2][x] + red[2][3][x];
    T2 = red[3][0][x] + red[3][1][x] + red[3][2][x] + red[3][3][x];
    float ap = 0.3f + 0.4f / (1.f + expf(-(S + apb[0])));
    float A  = T0 + ap * T1 + (1.f - ap) * T2 + ab[0];
    float al = 0.6f + 0.3f / (1.f + expf(-A));
    planes[blockIdx.x * 80 + x]         = ap;
    planes[30720 + blockIdx.x * 80 + x] = al;
  }
}

// out = al*f_t_mod + (1-al)*(ap*f_t1_mod + (1-ap)*f_tm2)
__global__ __launch_bounds__(256) void final_kernel(
    const float* __restrict__ fm, const float* __restrict__ f2,
    const float* __restrict__ planes, float* __restrict__ out)
{
  size_t idx = ((size_t)blockIdx.x * 256 + threadIdx.x) * 4;
  if (idx >= (size_t)7864320) return;
  int bc = (int)(idx / 3840);
  int p  = (int)(idx % 3840);
  int b  = bc >> 8;
  int pix = b * 3840 + p;
  const float4 vm = *(const float4*)(fm + (size_t)bc * 3840 + p);
  const float4 v1 = *(const float4*)(fm + ((size_t)bc + 2048) * 3840 + p);
  const float4 v2 = *(const float4*)(f2 + (size_t)bc * 3840 + p);
  const float4 ap = *(const float4*)(planes + pix);
  const float4 al = *(const float4*)(planes + 30720 + pix);
  float4 r;
  r.x = al.x * vm.x + (1.f - al.x) * (ap.x * v1.x + (1.f - ap.x) * v2.x);
  r.y = al.y * vm.y + (1.f - al.y) * (ap.y * v1.y + (1.f - ap.y) * v2.y);
  r.z = al.z * vm.z + (1.f - al.z) * (ap.z * v1.z + (1.f - ap.z) * v2.z);
  r.w = al.w * vm.w + (1.f - al.w) * (ap.w * v1.w + (1.f - ap.w) * v2.w);
  *(float4*)(out + idx) = r;
}

// ---------------- launcher ----------------

extern "C" void kernel_launch(void* const* d_in, const int* in_sizes, int n_in,
                              void* d_out, int out_size, void* d_ws, size_t ws_size,
                              hipStream_t stream)
{
  const float* f_tm2 = (const float*)d_in[0];
  const float* f_tm1 = (const float*)d_in[1];
  const float* f_t   = (const float*)d_in[2];
  const float* ov_w1 = (const float*)d_in[3];
  const float* ov_b1 = (const float*)d_in[4];
  const float* bn1_g = (const float*)d_in[5];
  const float* bn1_b = (const float*)d_in[6];
  const float* bn1_m = (const float*)d_in[7];
  const float* bn1_v = (const float*)d_in[8];
  const float* ov_w2 = (const float*)d_in[9];
  const float* ov_b2 = (const float*)d_in[10];
  const float* bn2_g = (const float*)d_in[11];
  const float* bn2_b = (const float*)d_in[12];
  const float* bn2_m = (const float*)d_in[13];
  const float* bn2_v = (const float*)d_in[14];
  const float* g_w   = (const float*)d_in[15];
  const float* g_b   = (const float*)d_in[16];
  const float* fc1_w = (const float*)d_in[17];
  const float* fc1_b = (const float*)d_in[18];
  const float* fc2_w = (const float*)d_in[19];
  const float* fc2_b = (const float*)d_in[20];
  const float* ap_w  = (const float*)d_in[21];
  const float* ap_b  = (const float*)d_in[22];
  const float* a_w   = (const float*)d_in[23];
  const float* a_b   = (const float*)d_in[24];

  // workspace layout (fm aliases in1p/wt1/wt2/h1p-head: those are dead by dw)
  char* ws = (char*)d_ws;
  float* fm            = (float*)ws;                    // 62,914,560 B
  __hip_bfloat16* in1p = (__hip_bfloat16*)ws;           // 53,673,984 B (8x52x84x768)
  __hip_bfloat16* wt1  = (__hip_bfloat16*)(ws + 53673984);  //  3,538,944 B
  __hip_bfloat16* wt2  = (__hip_bfloat16*)(ws + 57212928);  //  1,179,648 B
  __hip_bfloat16* h1p  = (__hip_bfloat16*)(ws + 58392576);  // 20,185,088 B (8x56x88x256)
  float* gpool         = (float*)(ws + 78577664);       //  8 KB
  float* gapv          = (float*)(ws + 78585856);       // 16 KB
  float* Gv            = (float*)(ws + 78602240);       //  8 KB
  float* out1          = (float*)(ws + 78610432);       // 32 KB
  float* wdw           = (float*)(ws + 78643200);       // 144 KB
  float* planes        = (float*)(ws + 78790656);       // 240 KB
  float* cst           = (float*)(ws + 79036416);       //  4 KB  (total ~75.4 MiB)

  hipMemsetAsync(in1p, 0, 53673984, stream);   // zero borders for conv1
  hipMemsetAsync(h1p, 0, 20185088, stream);    // zero borders for conv2
  hipMemsetAsync(gpool, 0, 8192, stream);      // pooled-sum accumulator

  prep_consts_kernel<<<1, 256, 0, stream>>>(ov_b1, bn1_g, bn1_b, bn1_m, bn1_v,
                                            ov_b2, bn2_g, bn2_b, bn2_m, bn2_v, cst);
  pad_concat_kernel<<<384, 256, 0, stream>>>(f_tm2, f_tm1, f_t, in1p);
  repack_w_kernel<<<6912, 256, 0, stream>>>(ov_w1, wt1, 256, 768);
  repack_w_kernel<<<2304, 256, 0, stream>>>(ov_w2, wt2, 256, 256);
  gap_kernel<<<4096, 256, 0, stream>>>(f_t, f_tm1, gapv);

  // conv1: 768ch dil=2 -> h1p (bf16, padded +4);  conv2: 256ch dil=4 -> pooled sums
  conv_mfma_kernel<768, 52, 84, 2, 0><<<480, 256, 0, stream>>>(in1p, wt1, cst, cst + 256, h1p, nullptr);
  conv_mfma_kernel<256, 56, 88, 4, 1><<<480, 256, 0, stream>>>(h1p, wt2, cst + 512, cst + 768, nullptr, gpool);

  fcG_kernel<<<8, 256, 0, stream>>>(gpool, g_w, g_b, Gv);
  fc1_kernel<<<32, 256, 0, stream>>>(Gv, gapv, fc1_w, fc1_b, out1);
  fc2_kernel<<<144, 256, 0, stream>>>(out1, fc2_w, fc2_b, wdw);
  dw_kernel<<<4096, 256, 0, stream>>>(f_t, f_tm1, wdw, fm);
  alpha_kernel<<<384, 320, 0, stream>>>(fm, f_tm2, ap_w, ap_b, a_w, a_b, planes);
  final_kernel<<<7680, 256, 0, stream>>>(fm, f_tm2, planes, (float*)d_out);
}

// Round 2
// 556.463 us; speedup vs baseline: 1.2160x; 1.2160x over previous
//
#include <hip/hip_runtime.h>
#include <hip/hip_bf16.h>
#include <math.h>

// ---------------------------------------------------------------------------
// ContMixT: f_concat -> conv3x3(d2) BN ReLU -> conv3x3(d4) BN ReLU -> pool ->
// 1x1 -> fc -> per-(batch,channel) 3x3 depthwise -> two 1x1 gates -> blend.
// conv1/conv2 run as bf16 MFMA implicit GEMM (m97-style: 128x128 tile, BK=64,
// global_load_lds width=16, xor-swizzled LDS). Everything after the mean-pool
// is fp32 (error through the pool path is attenuated ~62x).
// R1: pad_concat rewritten as tiled transpose (2304 blocks, float4 loads,
//     16B bf16x8 stores) — was latency-bound at 160us (16% occ, 8% HBM).
// ---------------------------------------------------------------------------

typedef __bf16 bf16x8 __attribute__((ext_vector_type(8)));
typedef float f32x4 __attribute__((ext_vector_type(4)));
typedef __attribute__((address_space(1))) void as1_void;
typedef __attribute__((address_space(3))) void as3_void;

// ---------------- small prep kernels ----------------

// BN folding: A = g/sqrt(v+eps), Bc = (conv_bias - m)*A + b  (256 threads)
__global__ __launch_bounds__(256) void prep_consts_kernel(
    const float* __restrict__ ob1, const float* __restrict__ g1, const float* __restrict__ b1,
    const float* __restrict__ m1, const float* __restrict__ v1,
    const float* __restrict__ ob2, const float* __restrict__ g2, const float* __restrict__ b2,
    const float* __restrict__ m2, const float* __restrict__ v2,
    float* __restrict__ cst)
{
  int i = threadIdx.x;
  float a1 = g1[i] / sqrtf(v1[i] + 1e-5f);
  cst[i]       = a1;
  cst[256 + i] = (ob1[i] - m1[i]) * a1 + b1[i];
  float a2 = g2[i] / sqrtf(v2[i] + 1e-5f);
  cst[512 + i] = a2;
  cst[768 + i] = (ob2[i] - m2[i]) * a2 + b2[i];
}

// NCHW fp32 x3 -> padded NHWC bf16 [b][y+2][x+2][c], c = [f_tm2 | f_tm1 | f_t]
// One block per (b, y, 128-channel group). Phase 1: float4 loads -> fp32 LDS
// [c][x] (stride 85: odd -> bank rotation). Phase 2: 8 LDS reads -> 16B store.
__global__ __launch_bounds__(256) void pad_concat_kernel(
    const float* __restrict__ f2, const float* __restrict__ f1, const float* __restrict__ f0,
    __hip_bfloat16* __restrict__ out)
{
  int bid = blockIdx.x;
  const int cg = bid % 6; bid /= 6;
  const int y = bid % 48;
  const int b = bid / 48;

  __shared__ float tile[128 * 85];

  const float* src = (cg < 2) ? f2 : ((cg < 4) ? f1 : f0);
  const int ccbase = (cg & 1) * 128;

  // phase 1: 128 c x 20 x4 = 2560 float4 loads, 10 per thread
#pragma unroll
  for (int it = 0; it < 10; it++) {
    const int idx = it * 256 + threadIdx.x;
    const int cl = idx / 20, x4 = idx % 20;
    const float4 v = *(const float4*)(src +
        (((size_t)b * 256 + ccbase + cl) * 48 + y) * 80 + x4 * 4);
    float* t = tile + cl * 85 + x4 * 4;
    t[0] = v.x; t[1] = v.y; t[2] = v.z; t[3] = v.w;
  }
  __syncthreads();

  // phase 2: 80 x x 16 chunks = 1280 16B stores, 5 per thread
  __hip_bfloat16* obase = out + ((size_t)(b * 52 + y + 2) * 84 + 2) * 768 + cg * 128;
#pragma unroll
  for (int it = 0; it < 5; it++) {
    const int idx = it * 256 + threadIdx.x;
    const int chunk = idx & 15, x = idx >> 4;
    const float* t = tile + chunk * 8 * 85 + x;
    union { __hip_bfloat16 h[8]; uint4 u; } pk;
#pragma unroll
    for (int j = 0; j < 8; j++) pk.h[j] = __float2bfloat16(t[j * 85]);
    *(uint4*)(obase + (size_t)x * 768 + chunk * 8) = pk.u;
  }
}

// OIHW fp32 -> [tap][oc][ic] bf16
__global__ __launch_bounds__(256) void repack_w_kernel(
    const float* __restrict__ w, __hip_bfloat16* __restrict__ out, int OC, int IC)
{
  int idx = blockIdx.x * 256 + threadIdx.x;
  if (idx >= OC * IC * 9) return;
  int ic = idx % IC;
  int t = idx / IC;
  int oc = t % OC;
  int tap = t / OC;
  out[idx] = __float2bfloat16(w[(oc * IC + ic) * 9 + tap]);
}

// gap[i][c] = mean_{y,x} Fs[i][c], Fs = [f_t ; f_t_minus_1]
__global__ __launch_bounds__(256) void gap_kernel(
    const float* __restrict__ f0, const float* __restrict__ f1, float* __restrict__ gapv)
{
  int i = blockIdx.x >> 8, c = blockIdx.x & 255;
  const float* src = (i < 8) ? (f0 + ((size_t)i * 256 + c) * 3840)
                             : (f1 + ((size_t)(i - 8) * 256 + c) * 3840);
  float s = 0.f;
  for (int k = threadIdx.x; k < 3840; k += 256) s += src[k];
  for (int off = 32; off; off >>= 1) s += __shfl_xor(s, off);
  __shared__ float red[4];
  if ((threadIdx.x & 63) == 0) red[threadIdx.x >> 6] = s;
  __syncthreads();
  if (threadIdx.x == 0)
    gapv[blockIdx.x] = (red[0] + red[1] + red[2] + red[3]) * (1.f / 3840.f);
}

// ---------------- MFMA implicit-GEMM conv ----------------
// Tile: M=128 pixels (8 rows x 16 x) x N=128 oc, BK=64, 4 waves, wave = 64x64.
// A LDS [m][64c], B LDS [oc][64c], both 128B rows with 16B-chunk xor swizzle
// (chunk col = j ^ (row&7)) so ds_read_b128 is conflict-free and the
// global_load_lds contiguous-write constraint (m104) is respected by
// permuting the *source* chunk per lane.
// MODE 0: BN+ReLU -> bf16 NHWC padded(+4) store (conv1 -> conv2 input)
// MODE 1: BN+ReLU -> pooled per-(b,oc) sums via atomics (h2 never stored)
template <int CIN, int HP, int WP, int DIL, int MODE>
__global__ __launch_bounds__(256) void conv_mfma_kernel(
    const __hip_bfloat16* __restrict__ inp, const __hip_bfloat16* __restrict__ wt,
    const float* __restrict__ bnA, const float* __restrict__ bnB,
    __hip_bfloat16* __restrict__ outp, float* __restrict__ gpool)
{
  __shared__ unsigned short As[8192] __attribute__((aligned(16)));
  __shared__ unsigned short Bs[8192] __attribute__((aligned(16)));

  int bid = blockIdx.x;
  const int ocb = bid & 1; bid >>= 1;
  const int xb = bid % 5; bid /= 5;
  const int yb = bid % 6; bid /= 6;
  const int b = bid;
  const int y0 = yb * 8, x0 = xb * 16, oc0 = ocb * 128;

  const int t = threadIdx.x;
  const int w = t >> 6, l = t & 63;
  const int col16 = l & 15, quad = l >> 4;
  const int wm = w >> 1, wn = w & 1;
  const int rsub = l >> 3;          // row within an 8-row staging chunk
  const int jj = (l & 7) ^ rsub;    // swizzled source 16B-chunk

  f32x4 acc[4][4];
  const f32x4 zf = {0.f, 0.f, 0.f, 0.f};
#pragma unroll
  for (int i = 0; i < 4; i++)
#pragma unroll
    for (int j = 0; j < 4; j++) acc[i][j] = zf;

  for (int tap = 0; tap < 9; tap++) {
    const int ty = tap / 3, tx = tap - ty * 3;
    const __hip_bfloat16* inBase =
        inp + ((size_t)(b * HP + y0 + DIL * ty) * WP + (x0 + DIL * tx)) * CIN + jj * 8;
    const __hip_bfloat16* wBase = wt + (size_t)(tap * 256 + oc0) * CIN + jj * 8;
    for (int c0 = 0; c0 < CIN; c0 += 64) {
      __syncthreads();
#pragma unroll
      for (int i = 0; i < 4; i++) {            // A: 128 pixels x 64 ch
        const int q = i * 4 + w;
        const int m = q * 8 + rsub;
        const int ry = m >> 4, rx = m & 15;
        const __hip_bfloat16* gp = inBase + (ry * WP + rx) * CIN + c0;
        __builtin_amdgcn_global_load_lds((as1_void*)gp,
            (as3_void*)((char*)As + q * 1024), 16, 0, 0);
      }
#pragma unroll
      for (int i = 0; i < 4; i++) {            // B: 128 oc x 64 ch
        const int q = i * 4 + w;
        const int n = q * 8 + rsub;
        const __hip_bfloat16* gp = wBase + n * CIN + c0;
        __builtin_amdgcn_global_load_lds((as1_void*)gp,
            (as3_void*)((char*)Bs + q * 1024), 16, 0, 0);
      }
      __syncthreads();
#pragma unroll
      for (int kiter = 0; kiter < 2; kiter++) {
        bf16x8 af[4], bg[4];
#pragma unroll
        for (int fi = 0; fi < 4; fi++) {       // A frag: m = lane&15
          const int m = wm * 64 + fi * 16 + col16;
          const int jc = (kiter * 4 + quad) ^ (m & 7);
          af[fi] = *(const bf16x8*)((const char*)As + m * 128 + jc * 16);
        }
#pragma unroll
        for (int fi = 0; fi < 4; fi++) {       // B frag: n = lane&15
          const int n = wn * 64 + fi * 16 + col16;
          const int jc = (kiter * 4 + quad) ^ (n & 7);
          bg[fi] = *(const bf16x8*)((const char*)Bs + n * 128 + jc * 16);
        }
#pragma unroll
        for (int fm_ = 0; fm_ < 4; fm_++)
#pragma unroll
          for (int fn_ = 0; fn_ < 4; fn_++)
            acc[fm_][fn_] = __builtin_amdgcn_mfma_f32_16x16x32_bf16(
                af[fm_], bg[fn_], acc[fm_][fn_], 0, 0, 0);
      }
    }
  }

  if (MODE == 0) {
    // C/D layout: col = lane&15 (= oc), row = quad*4 + r (= pixel)  [m89/m91]
#pragma unroll
    for (int fn_ = 0; fn_ < 4; fn_++) {
      const int oc = oc0 + wn * 64 + fn_ * 16 + col16;
      const float sa = bnA[oc], sb = bnB[oc];
#pragma unroll
      for (int fm_ = 0; fm_ < 4; fm_++) {
#pragma unroll
        for (int r = 0; r < 4; r++) {
          const int m = wm * 64 + fm_ * 16 + quad * 4 + r;
          const int y = y0 + (m >> 4), x = x0 + (m & 15);
          const float v = fmaxf(acc[fm_][fn_][r] * sa + sb, 0.f);
          outp[((size_t)(b * 56 + y + 4) * 88 + (x + 4)) * 256 + oc] = __float2bfloat16(v);
        }
      }
    }
  } else {
#pragma unroll
    for (int fn_ = 0; fn_ < 4; fn_++) {
      const int oc = oc0 + wn * 64 + fn_ * 16 + col16;
      const float sa = bnA[oc], sb = bnB[oc];
      float cs = 0.f;
#pragma unroll
      for (int fm_ = 0; fm_ < 4; fm_++)
#pragma unroll
        for (int r = 0; r < 4; r++)
          cs += fmaxf(acc[fm_][fn_][r] * sa + sb, 0.f);
      cs += __shfl_xor(cs, 16);   // combine the 4 quads holding this column
      cs += __shfl_xor(cs, 32);
      if (quad == 0) atomicAdd(&gpool[b * 256 + oc], cs);
    }
  }
}

// ---------------- FC chain (fp32) ----------------

// G[b][oc] = g_b[oc] + sum_c gpool[b][c]/3840 * g_w[oc][c]
__global__ __launch_bounds__(256) void fcG_kernel(
    const float* __restrict__ gpool, const float* __restrict__ gw,
    const float* __restrict__ gb, float* __restrict__ G)
{
  int b = blockIdx.x, oc = threadIdx.x;
  __shared__ float pool[256];
  pool[oc] = gpool[b * 256 + oc] * (1.f / 3840.f);
  __syncthreads();
  float s = gb[oc];
  const float* wr = gw + oc * 256;
  for (int c2 = 0; c2 < 256; c2++) s += pool[c2] * wr[c2];
  G[b * 256 + oc] = s;
}

// out1[j][i] = silu(fc_in[i] . fc1_w[j] + b[j]); fc_in = [G[i/2] | gap[i]]
__global__ __launch_bounds__(256) void fc1_kernel(
    const float* __restrict__ G, const float* __restrict__ gapv,
    const float* __restrict__ w, const float* __restrict__ bias,
    float* __restrict__ out1)
{
  __shared__ float fin[16][513];
  for (int idx = threadIdx.x; idx < 16 * 512; idx += 256) {
    int i = idx >> 9, k = idx & 511;
    fin[i][k] = (k < 256) ? G[(i >> 1) * 256 + k] : gapv[i * 256 + (k - 256)];
  }
  __syncthreads();
  int g = blockIdx.x * 256 + threadIdx.x;
  int j = g >> 4, i = g & 15;
  float s = bias[j];
  const float* wr = w + j * 512;
  for (int k = 0; k < 512; k++) s += fin[i][k] * wr[k];
  out1[j * 16 + i] = s / (1.f + expf(-s));
}

// wdw[i][j] = out1[i] . fc2_w[j] + b[j]   (j in 0..2303)
__global__ __launch_bounds__(256) void fc2_kernel(
    const float* __restrict__ out1, const float* __restrict__ w,
    const float* __restrict__ bias, float* __restrict__ wdw)
{
  __shared__ float fin[16][513];
  for (int idx = threadIdx.x; idx < 16 * 512; idx += 256) {
    int i = idx >> 9, k = idx & 511;
    fin[i][k] = out1[k * 16 + i];
  }
  __syncthreads();
  int g = blockIdx.x * 256 + threadIdx.x;
  int j = g >> 4, i = g & 15;
  float s = bias[j];
  const float* wr = w + j * 512;
  for (int k = 0; k < 512; k++) s += fin[i][k] * wr[k];
  wdw[i * 2304 + j] = s;
}

// per-(i,c) 3x3 depthwise, pad 1: fm = dwconv(Fs, wdw)
__global__ __launch_bounds__(256) void dw_kernel(
    const float* __restrict__ f0, const float* __restrict__ f1,
    const float* __restrict__ wdw, float* __restrict__ fm)
{
  int i = blockIdx.x >> 8, c = blockIdx.x & 255;
  const float* src = (i < 8) ? (f0 + ((size_t)i * 256 + c) * 3840)
                             : (f1 + ((size_t)(i - 8) * 256 + c) * 3840);
  float* dst = fm + ((size_t)i * 256 + c) * 3840;
  __shared__ float w9[9];
  if (threadIdx.x < 9) w9[threadIdx.x] = wdw[i * 2304 + c * 9 + threadIdx.x];
  __syncthreads();
  for (int p = threadIdx.x; p < 3840; p += 256) {
    int y = p / 80, x = p - y * 80;
    float s = 0.f;
#pragma unroll
    for (int ky = 0; ky < 3; ky++) {
      int yy = y + ky - 1;
      if (yy < 0 || yy >= 48) continue;
#pragma unroll
      for (int kx = 0; kx < 3; kx++) {
        int xx = x + kx - 1;
        if (xx < 0 || xx >= 80) continue;
        s += w9[ky * 3 + kx] * src[yy * 80 + xx];
      }
    }
    dst[p] = s;
  }
}

// per-pixel channel reductions -> alpha_prev, alpha planes
// (sum over f_prev folds: a_w.f_prev = ap*T1 + (1-ap)*T2, ap scalar per pixel)
__global__ __launch_bounds__(320) void alpha_kernel(
    const float* __restrict__ fm, const float* __restrict__ f2,
    const float* __restrict__ apw, const float* __restrict__ apb,
    const float* __restrict__ aw, const float* __restrict__ ab,
    float* __restrict__ planes)
{
  int b = blockIdx.x / 48, y = blockIdx.x % 48;
  int x = threadIdx.x % 80, g = threadIdx.x / 80;  // g in 0..3: 64-ch slices
  const float* ftm  = fm + ((size_t)b * 256) * 3840 + y * 80 + x;
  const float* ft1m = fm + ((size_t)(b + 8) * 256) * 3840 + y * 80 + x;
  const float* ptm2 = f2 + ((size_t)b * 256) * 3840 + y * 80 + x;
  float S = 0.f, T0 = 0.f, T1 = 0.f, T2 = 0.f;
  for (int cc = 0; cc < 64; cc++) {
    int c = g * 64 + cc;
    float v1 = ft1m[(size_t)c * 3840];
    float v2 = ptm2[(size_t)c * 3840];
    float v0 = ftm[(size_t)c * 3840];
    S  += apw[c] * v1 + apw[256 + c] * v2;
    T0 += aw[c] * v0;
    T1 += aw[256 + c] * v1;
    T2 += aw[256 + c] * v2;
  }
  __shared__ float red[4][4][80];
  red[0][g][x] = S; red[1][g][x] = T0; red[2][g][x] = T1; red[3][g][x] = T2;
  __syncthreads();
  if (g == 0) {
    S  = red[0][0][x] + red[0][1][x] + red[0][2][x] + red[0][3][x];
    T0 = red[1][0][x] + red[1][1][x] + red[1][2][x] + red[1][3][x];
    T1 = red[2][0][x] + red[2][1][x] + red[2][2][x] + red[2][3][x];
    T2 = red[3][0][x] + red[3][1][x] + red[3][2][x] + red[3][3][x];
    float ap = 0.3f + 0.4f / (1.f + expf(-(S + apb[0])));
    float A  = T0 + ap * T1 + (1.f - ap) * T2 + ab[0];
    float al = 0.6f + 0.3f / (1.f + expf(-A));
    planes[blockIdx.x * 80 + x]         = ap;
    planes[30720 + blockIdx.x * 80 + x] = al;
  }
}

// out = al*f_t_mod + (1-al)*(ap*f_t1_mod + (1-ap)*f_tm2)
__global__ __launch_bounds__(256) void final_kernel(
    const float* __restrict__ fm, const float* __restrict__ f2,
    const float* __restrict__ planes, float* __restrict__ out)
{
  size_t idx = ((size_t)blockIdx.x * 256 + threadIdx.x) * 4;
  if (idx >= (size_t)7864320) return;
  int bc = (int)(idx / 3840);
  int p  = (int)(idx % 3840);
  int b  = bc >> 8;
  int pix = b * 3840 + p;
  const float4 vm = *(const float4*)(fm + (size_t)bc * 3840 + p);
  const float4 v1 = *(const float4*)(fm + ((size_t)bc + 2048) * 3840 + p);
  const float4 v2 = *(const float4*)(f2 + (size_t)bc * 3840 + p);
  const float4 ap = *(const float4*)(planes + pix);
  const float4 al = *(const float4*)(planes + 30720 + pix);
  float4 r;
  r.x = al.x * vm.x + (1.f - al.x) * (ap.x * v1.x + (1.f - ap.x) * v2.x);
  r.y = al.y * vm.y + (1.f - al.y) * (ap.y * v1.y + (1.f - ap.y) * v2.y);
  r.z = al.z * vm.z + (1.f - al.z) * (ap.z * v1.z + (1.f - ap.z) * v2.z);
  r.w = al.w * vm.w + (1.f - al.w) * (ap.w * v1.w + (1.f - ap.w) * v2.w);
  *(float4*)(out + idx) = r;
}

// ---------------- launcher ----------------

extern "C" void kernel_launch(void* const* d_in, const int* in_sizes, int n_in,
                              void* d_out, int out_size, void* d_ws, size_t ws_size,
                              hipStream_t stream)
{
  const float* f_tm2 = (const float*)d_in[0];
  const float* f_tm1 = (const float*)d_in[1];
  const float* f_t   = (const float*)d_in[2];
  const float* ov_w1 = (const float*)d_in[3];
  const float* ov_b1 = (const float*)d_in[4];
  const float* bn1_g = (const float*)d_in[5];
  const float* bn1_b = (const float*)d_in[6];
  const float* bn1_m = (const float*)d_in[7];
  const float* bn1_v = (const float*)d_in[8];
  const float* ov_w2 = (const float*)d_in[9];
  const float* ov_b2 = (const float*)d_in[10];
  const float* bn2_g = (const float*)d_in[11];
  const float* bn2_b = (const float*)d_in[12];
  const float* bn2_m = (const float*)d_in[13];
  const float* bn2_v = (const float*)d_in[14];
  const float* g_w   = (const float*)d_in[15];
  const float* g_b   = (const float*)d_in[16];
  const float* fc1_w = (const float*)d_in[17];
  const float* fc1_b = (const float*)d_in[18];
  const float* fc2_w = (const float*)d_in[19];
  const float* fc2_b = (const float*)d_in[20];
  const float* ap_w  = (const float*)d_in[21];
  const float* ap_b  = (const float*)d_in[22];
  const float* a_w   = (const float*)d_in[23];
  const float* a_b   = (const float*)d_in[24];

  // workspace layout (fm aliases in1p/wt1/wt2/h1p-head: those are dead by dw)
  char* ws = (char*)d_ws;
  float* fm            = (float*)ws;                    // 62,914,560 B
  __hip_bfloat16* in1p = (__hip_bfloat16*)ws;           // 53,673,984 B (8x52x84x768)
  __hip_bfloat16* wt1  = (__hip_bfloat16*)(ws + 53673984);  //  3,538,944 B
  __hip_bfloat16* wt2  = (__hip_bfloat16*)(ws + 57212928);  //  1,179,648 B
  __hip_bfloat16* h1p  = (__hip_bfloat16*)(ws + 58392576);  // 20,185,088 B (8x56x88x256)
  float* gpool         = (float*)(ws + 78577664);       //  8 KB
  float* gapv          = (float*)(ws + 78585856);       // 16 KB
  float* Gv            = (float*)(ws + 78602240);       //  8 KB
  float* out1          = (float*)(ws + 78610432);       // 32 KB
  float* wdw           = (float*)(ws + 78643200);       // 144 KB
  float* planes        = (float*)(ws + 78790656);       // 240 KB
  float* cst           = (float*)(ws + 79036416);       //  4 KB  (total ~75.4 MiB)

  hipMemsetAsync(in1p, 0, 53673984, stream);   // zero borders for conv1
  hipMemsetAsync(h1p, 0, 20185088, stream);    // zero borders for conv2
  hipMemsetAsync(gpool, 0, 8192, stream);      // pooled-sum accumulator

  prep_consts_kernel<<<1, 256, 0, stream>>>(ov_b1, bn1_g, bn1_b, bn1_m, bn1_v,
                                            ov_b2, bn2_g, bn2_b, bn2_m, bn2_v, cst);
  pad_concat_kernel<<<2304, 256, 0, stream>>>(f_tm2, f_tm1, f_t, in1p);
  repack_w_kernel<<<6912, 256, 0, stream>>>(ov_w1, wt1, 256, 768);
  repack_w_kernel<<<2304, 256, 0, stream>>>(ov_w2, wt2, 256, 256);
  gap_kernel<<<4096, 256, 0, stream>>>(f_t, f_tm1, gapv);

  // conv1: 768ch dil=2 -> h1p (bf16, padded +4);  conv2: 256ch dil=4 -> pooled sums
  conv_mfma_kernel<768, 52, 84, 2, 0><<<480, 256, 0, stream>>>(in1p, wt1, cst, cst + 256, h1p, nullptr);
  conv_mfma_kernel<256, 56, 88, 4, 1><<<480, 256, 0, stream>>>(h1p, wt2, cst + 512, cst + 768, nullptr, gpool);

  fcG_kernel<<<8, 256, 0, stream>>>(gpool, g_w, g_b, Gv);
  fc1_kernel<<<32, 256, 0, stream>>>(Gv, gapv, fc1_w, fc1_b, out1);
  fc2_kernel<<<144, 256, 0, stream>>>(out1, fc2_w, fc2_b, wdw);
  dw_kernel<<<4096, 256, 0, stream>>>(f_t, f_tm1, wdw, fm);
  alpha_kernel<<<384, 320, 0, stream>>>(fm, f_tm2, ap_w, ap_b, a_w, a_b, planes);
  final_kernel<<<7680, 256, 0, stream>>>(fm, f_tm2, planes, (float*)d_out);
}